// Round 1
// 788.058 us; speedup vs baseline: 1.0031x; 1.0031x over previous
//
#include <hip/hip_runtime.h>
#include <cstddef>

// DifferentiableRollout: x_{t+1} = x + DT * ( tanh([x,u]@W1 + b1) @ W2 + b2 )
// B=1024, T=200, SD=64, CD=32, H=512.  fp32 only (R0: fp32 reorder noise
// alone -> absmax 0.25 of 1.245 threshold; bf16 would amplify past it).
//
// R5: fit the weights in the 128-VGPR envelope the allocator actually grants.
//   - GEMM1: thread (g=tid>>9, j=tid&511) owns W1[k in 48g..48g+48)][j]
//     (48 regs).  g=1 writes rank-48 partials to LDS; g=0 adds its half,
//     + b1, tanh -> hbuf.  x read as wave-uniform float4 broadcast (free).
//   - GEMM2: wave wv (0..15) owns W2 rows [32wv,32wv+32); lane sl holds
//     W2[.][sl] (32 regs).  Rank-32 partials -> part2[r][wv][sl]
//     (lane-consecutive, conflict-free), 16-chunk reduce by tid<256.
//   - 256 blocks -> 1 block/CU, 16 waves/CU.  4 barriers/step.
//   - Controls prefetched one step ahead by otherwise-idle g=1 threads.
//
// R6 (this round): __launch_bounds__(1024, 4).
//   R5 post-mortem: VGPR_Count=60 < 80 weight floats -> weights were NOT
//   register-resident.  Without a min-waves arg the allocator targeted
//   2 blocks/CU (VGPR<=64) -- unreachable with a 256-block grid on 256 CUs
//   -- and rematerialized the weight arrays as per-step global loads
//   (L2-hit, invisible in FETCH_SIZE) + addressing: measured ~7430 VALU
//   cycles/SIMD/step vs 2560 core-FMA cycles (2.9x inflation), 23% idle
//   from unhidden L2 latency.  Pinning 4 waves/EU (= the 1 block/CU we
//   already have) raises the budget to 128 VGPRs; demand ~110 fits.

constexpr int B_  = 1024;
constexpr int T_  = 200;
constexpr int SD_ = 64;
constexpr int CD_ = 32;
constexpr int H_  = 512;
constexpr int KD_ = SD_ + CD_;   // 96
constexpr float DT_ = 0.1f;
constexpr int ROWS_ = 4;
constexpr int THREADS_ = 1024;
constexpr int KHALF_ = 48;       // K split per g
constexpr int CHUNK_ = 32;       // W2 rows per wave (H / 16 waves)

__global__ __launch_bounds__(THREADS_, 4)
void rollout_split_kernel(
    const float* __restrict__ x0,     // [B, SD]
    const float* __restrict__ ctrl,   // [B, T, CD]
    const float* __restrict__ W1,     // [KD, H]
    const float* __restrict__ b1,     // [H]
    const float* __restrict__ W2,     // [H, SD]
    const float* __restrict__ b2,     // [SD]
    float* __restrict__ out)          // [B, T+1, SD]
{
    __shared__ float xcT[KD_][ROWS_];        // state+control, transposed (16B rows)
    __shared__ float part1[ROWS_][H_];       // GEMM1 rank-48 partials (g=1)
    __shared__ float hbuf[ROWS_][H_];        // activations
    __shared__ float part2[ROWS_][16][SD_];  // GEMM2 partials [r][wv][s]

    const int tid = threadIdx.x;
    const int r0  = blockIdx.x * ROWS_;

    // ---- GEMM1 mapping: half-column of W1 in registers ----
    const int j     = tid & (H_ - 1);   // 0..511
    const int g     = tid >> 9;         // 0 or 1 (wave-uniform)
    const int kbase = g * KHALF_;
    float w1p[KHALF_];
    #pragma unroll
    for (int i = 0; i < KHALF_; ++i)
        w1p[i] = W1[(size_t)(kbase + i) * H_ + j];       // coalesced

    // ---- GEMM2 mapping: 32-row W2 chunk per wave ----
    const int wv = tid >> 6;            // 0..15 (wave id)
    const int sl = tid & 63;
    const int jb = wv * CHUNK_;
    float w2p[CHUNK_];
    #pragma unroll
    for (int i = 0; i < CHUNK_; ++i)
        w2p[i] = W2[(size_t)(jb + i) * SD_ + sl];        // coalesced

    const float bj = b1[j];             // used by g==0 finishers

    // reduce/update mapping (tid < 256)
    const int rf = (tid >> 6) & 3;
    const int sf = tid & 63;
    const float bs = b2[sf];

    // ctrl loader: tids [512, 640) -- g==1 threads, idle during tanh phase
    const int  lt = tid - 512;
    const bool loader = (lt >= 0) && (lt < ROWS_ * CD_);
    const int  lr = (lt >> 5) & 3;
    const int  lc = lt & 31;
    const size_t ctrl_base = (size_t)(r0 + lr) * T_ * CD_ + lc;

    // ---- init: x0 into xcT + states[:,0,:], ctrl[0] into xcT ----
    if (tid < ROWS_ * SD_) {
        const float v = x0[(size_t)(r0 + rf) * SD_ + sf];
        xcT[sf][rf] = v;
        out[(size_t)(r0 + rf) * (T_ + 1) * SD_ + sf] = v;
    }
    if (loader) xcT[SD_ + lc][lr] = ctrl[ctrl_base];
    __syncthreads();

    for (int t = 0; t < T_; ++t) {
        // ---- prefetch next step's controls into a register ----
        float cpre = 0.f;
        if (loader && (t + 1 < T_))
            cpre = ctrl[ctrl_base + (size_t)(t + 1) * CD_];

        // ---- GEMM1 rank-48 partials: 4 rows per thread ----
        float a0 = 0.f, a1 = 0.f, a2 = 0.f, a3 = 0.f;
        #pragma unroll
        for (int i = 0; i < KHALF_; ++i) {
            const float4 xv = *(const float4*)&xcT[kbase + i][0];  // broadcast
            const float  w  = w1p[i];
            a0 += xv.x * w;
            a1 += xv.y * w;
            a2 += xv.z * w;
            a3 += xv.w * w;
        }
        if (g == 1) {
            part1[0][j] = a0;  part1[1][j] = a1;   // lane-consecutive
            part1[2][j] = a2;  part1[3][j] = a3;
        }
        __syncthreads();   // A: part1 visible; all xcT reads for step t done

        if (g == 0) {
            hbuf[0][j] = tanhf(bj + a0 + part1[0][j]);
            hbuf[1][j] = tanhf(bj + a1 + part1[1][j]);
            hbuf[2][j] = tanhf(bj + a2 + part1[2][j]);
            hbuf[3][j] = tanhf(bj + a3 + part1[3][j]);
        } else if (loader && (t + 1 < T_)) {
            xcT[SD_ + lc][lr] = cpre;   // safe: step-t xcT reads done at A
        }
        __syncthreads();   // B: hbuf visible

        // ---- GEMM2 rank-32 partials: wave wv covers j in [jb, jb+32) ----
        #pragma unroll
        for (int r = 0; r < ROWS_; ++r) {
            float p = 0.f;
            #pragma unroll
            for (int i4 = 0; i4 < CHUNK_; i4 += 4) {
                const float4 hv = *(const float4*)&hbuf[r][jb + i4];  // broadcast
                p += hv.x * w2p[i4]     + hv.y * w2p[i4 + 1]
                   + hv.z * w2p[i4 + 2] + hv.w * w2p[i4 + 3];
            }
            part2[r][wv][sl] = p;       // lane-consecutive: conflict-free
        }
        __syncthreads();   // C: part2 visible

        // ---- 16-chunk reduce + state update: tid < 256 ----
        if (tid < ROWS_ * SD_) {
            float acc = part2[rf][0][sf];
            #pragma unroll
            for (int c = 1; c < 16; ++c) acc += part2[rf][c][sf];
            const float xnew = xcT[sf][rf] + DT_ * (acc + bs);
            xcT[sf][rf] = xnew;
            out[(size_t)(r0 + rf) * (T_ + 1) * SD_ + (size_t)(t + 1) * SD_ + sf] = xnew;
        }
        __syncthreads();   // D: new state visible; part2 reads done
    }
}

extern "C" void kernel_launch(void* const* d_in, const int* in_sizes, int n_in,
                              void* d_out, int out_size, void* d_ws, size_t ws_size,
                              hipStream_t stream) {
    const float* x0   = (const float*)d_in[0];
    const float* ctrl = (const float*)d_in[1];
    const float* W1   = (const float*)d_in[2];
    const float* b1   = (const float*)d_in[3];
    const float* W2   = (const float*)d_in[4];
    const float* b2   = (const float*)d_in[5];
    float* out = (float*)d_out;

    dim3 grid(B_ / ROWS_);      // 256 blocks -> 1 per CU (persistent)
    dim3 block(THREADS_);
    rollout_split_kernel<<<grid, block, 0, stream>>>(x0, ctrl, W1, b1, W2, b2, out);
}

// Round 2
// 777.152 us; speedup vs baseline: 1.0172x; 1.0140x over previous
//
#include <hip/hip_runtime.h>
#include <cstddef>

// DifferentiableRollout: x_{t+1} = x + DT * ( tanh([x,u]@W1 + b1) @ W2 + b2 )
// B=1024, T=200, SD=64, CD=32, H=512.  fp32 only (R0: fp32 reorder noise
// alone -> absmax 0.25 of 1.245 threshold; bf16 would amplify past it).
//
// R5: weight-in-register split design.
//   - GEMM1: thread (g=tid>>9, j=tid&511) owns W1[k in 48g..48g+48)][j]
//     (48 regs).  g=1 writes rank-48 partials to LDS; g=0 adds its half,
//     + b1, tanh -> hbuf.  x read as wave-uniform float4 broadcast.
//   - GEMM2: wave wv (0..15) owns W2 rows [32wv,32wv+32); lane sl holds
//     W2[.][sl] (32 regs).  Rank-32 partials -> part2[r][wv][sl],
//     16-chunk reduce by tid<256.
//   - 256 blocks -> 1 block/CU, 16 waves/CU.  4 barriers/step.
//
// R6: __launch_bounds__(1024, 4) -> VGPR budget 128.  FAILED alone:
//   VGPR_Count stayed 60.  The cap was never binding -- the allocator
//   MINIMIZES pressure, and const __restrict__ invariant loads are
//   rematerializable, so LLVM sank all 80 weight loads into the t-loop:
//   327 KB/CU/step of L2 re-reads (16.7 TB total ~ 485 us at the 34.5 TB/s
//   L2 ceiling) + addressing VALU = the 2.9x VALU inflation we measured.
//
// R7 (this round): pin the weights live with opaque no-op inline asm.
//   asm volatile("" : "+v"(w)) redefines each weight as the output of an
//   opaque instruction -> not rematerializable -> must stay in a VGPR for
//   the whole kernel.  Demand ~110 fits the 128 budget from R6's bounds.
//   Verify via VGPR_Count ~104-128 in the counters.

constexpr int B_  = 1024;
constexpr int T_  = 200;
constexpr int SD_ = 64;
constexpr int CD_ = 32;
constexpr int H_  = 512;
constexpr int KD_ = SD_ + CD_;   // 96
constexpr float DT_ = 0.1f;
constexpr int ROWS_ = 4;
constexpr int THREADS_ = 1024;
constexpr int KHALF_ = 48;       // K split per g
constexpr int CHUNK_ = 32;       // W2 rows per wave (H / 16 waves)

__global__ __launch_bounds__(THREADS_, 4)
void rollout_split_kernel(
    const float* __restrict__ x0,     // [B, SD]
    const float* __restrict__ ctrl,   // [B, T, CD]
    const float* __restrict__ W1,     // [KD, H]
    const float* __restrict__ b1,     // [H]
    const float* __restrict__ W2,     // [H, SD]
    const float* __restrict__ b2,     // [SD]
    float* __restrict__ out)          // [B, T+1, SD]
{
    __shared__ float xcT[KD_][ROWS_];        // state+control, transposed (16B rows)
    __shared__ float part1[ROWS_][H_];       // GEMM1 rank-48 partials (g=1)
    __shared__ float hbuf[ROWS_][H_];        // activations
    __shared__ float part2[ROWS_][16][SD_];  // GEMM2 partials [r][wv][s]

    const int tid = threadIdx.x;
    const int r0  = blockIdx.x * ROWS_;

    // ---- GEMM1 mapping: half-column of W1 in registers ----
    const int j     = tid & (H_ - 1);   // 0..511
    const int g     = tid >> 9;         // 0 or 1 (wave-uniform)
    const int kbase = g * KHALF_;
    float w1p[KHALF_];
    #pragma unroll
    for (int i = 0; i < KHALF_; ++i)
        w1p[i] = W1[(size_t)(kbase + i) * H_ + j];       // coalesced

    // ---- GEMM2 mapping: 32-row W2 chunk per wave ----
    const int wv = tid >> 6;            // 0..15 (wave id)
    const int sl = tid & 63;
    const int jb = wv * CHUNK_;
    float w2p[CHUNK_];
    #pragma unroll
    for (int i = 0; i < CHUNK_; ++i)
        w2p[i] = W2[(size_t)(jb + i) * SD_ + sl];        // coalesced

    // ---- R7: pin weights live (defeat rematerialization) ----
    #pragma unroll
    for (int i = 0; i < KHALF_; ++i) asm volatile("" : "+v"(w1p[i]));
    #pragma unroll
    for (int i = 0; i < CHUNK_; ++i) asm volatile("" : "+v"(w2p[i]));

    const float bj = b1[j];             // used by g==0 finishers

    // reduce/update mapping (tid < 256)
    const int rf = (tid >> 6) & 3;
    const int sf = tid & 63;
    const float bs = b2[sf];

    // ctrl loader: tids [512, 640) -- g==1 threads, idle during tanh phase
    const int  lt = tid - 512;
    const bool loader = (lt >= 0) && (lt < ROWS_ * CD_);
    const int  lr = (lt >> 5) & 3;
    const int  lc = lt & 31;
    const size_t ctrl_base = (size_t)(r0 + lr) * T_ * CD_ + lc;

    // ---- init: x0 into xcT + states[:,0,:], ctrl[0] into xcT ----
    if (tid < ROWS_ * SD_) {
        const float v = x0[(size_t)(r0 + rf) * SD_ + sf];
        xcT[sf][rf] = v;
        out[(size_t)(r0 + rf) * (T_ + 1) * SD_ + sf] = v;
    }
    if (loader) xcT[SD_ + lc][lr] = ctrl[ctrl_base];
    __syncthreads();

    for (int t = 0; t < T_; ++t) {
        // ---- prefetch next step's controls into a register ----
        float cpre = 0.f;
        if (loader && (t + 1 < T_))
            cpre = ctrl[ctrl_base + (size_t)(t + 1) * CD_];

        // ---- GEMM1 rank-48 partials: 4 rows per thread ----
        float a0 = 0.f, a1 = 0.f, a2 = 0.f, a3 = 0.f;
        #pragma unroll
        for (int i = 0; i < KHALF_; ++i) {
            const float4 xv = *(const float4*)&xcT[kbase + i][0];  // broadcast
            const float  w  = w1p[i];
            a0 += xv.x * w;
            a1 += xv.y * w;
            a2 += xv.z * w;
            a3 += xv.w * w;
        }
        if (g == 1) {
            part1[0][j] = a0;  part1[1][j] = a1;   // lane-consecutive
            part1[2][j] = a2;  part1[3][j] = a3;
        }
        __syncthreads();   // A: part1 visible; all xcT reads for step t done

        if (g == 0) {
            hbuf[0][j] = tanhf(bj + a0 + part1[0][j]);
            hbuf[1][j] = tanhf(bj + a1 + part1[1][j]);
            hbuf[2][j] = tanhf(bj + a2 + part1[2][j]);
            hbuf[3][j] = tanhf(bj + a3 + part1[3][j]);
        } else if (loader && (t + 1 < T_)) {
            xcT[SD_ + lc][lr] = cpre;   // safe: step-t xcT reads done at A
        }
        __syncthreads();   // B: hbuf visible

        // ---- GEMM2 rank-32 partials: wave wv covers j in [jb, jb+32) ----
        #pragma unroll
        for (int r = 0; r < ROWS_; ++r) {
            float p = 0.f;
            #pragma unroll
            for (int i4 = 0; i4 < CHUNK_; i4 += 4) {
                const float4 hv = *(const float4*)&hbuf[r][jb + i4];  // broadcast
                p += hv.x * w2p[i4]     + hv.y * w2p[i4 + 1]
                   + hv.z * w2p[i4 + 2] + hv.w * w2p[i4 + 3];
            }
            part2[r][wv][sl] = p;       // lane-consecutive: conflict-free
        }
        __syncthreads();   // C: part2 visible

        // ---- 16-chunk reduce + state update: tid < 256 ----
        if (tid < ROWS_ * SD_) {
            float acc = part2[rf][0][sf];
            #pragma unroll
            for (int c = 1; c < 16; ++c) acc += part2[rf][c][sf];
            const float xnew = xcT[sf][rf] + DT_ * (acc + bs);
            xcT[sf][rf] = xnew;
            out[(size_t)(r0 + rf) * (T_ + 1) * SD_ + (size_t)(t + 1) * SD_ + sf] = xnew;
        }
        __syncthreads();   // D: new state visible; part2 reads done
    }
}

extern "C" void kernel_launch(void* const* d_in, const int* in_sizes, int n_in,
                              void* d_out, int out_size, void* d_ws, size_t ws_size,
                              hipStream_t stream) {
    const float* x0   = (const float*)d_in[0];
    const float* ctrl = (const float*)d_in[1];
    const float* W1   = (const float*)d_in[2];
    const float* b1   = (const float*)d_in[3];
    const float* W2   = (const float*)d_in[4];
    const float* b2   = (const float*)d_in[5];
    float* out = (float*)d_out;

    dim3 grid(B_ / ROWS_);      // 256 blocks -> 1 per CU (persistent)
    dim3 block(THREADS_);
    rollout_split_kernel<<<grid, block, 0, stream>>>(x0, ctrl, W1, b1, W2, b2, out);
}